// Round 3
// baseline (323.460 us; speedup 1.0000x reference)
//
#include <hip/hip_runtime.h>
#include <math.h>

#define BB 4
#define NSZ 2048
#define FDIM 128
#define ODIM 32
#define HH 8

typedef short short8 __attribute__((ext_vector_type(8)));
typedef float f32x4 __attribute__((ext_vector_type(4)));
typedef float f32x2 __attribute__((ext_vector_type(2)));

// workspace layout (float units)
#define WS_EAP  0                 // float2[B*H*N] (EA, EA2)   = 131072 floats
#define WS_EBP  131072            // EB[B*H*N] + EB2[B*H*N]    = 131072 floats (SoA)
#define WS_ADJB 262144            // u32[B*N*64]               = 524288 words
#define WS_WHF  786432            // bf16 Wh B-frags           = 1048576 floats (4MB)
// whf: int4[((b*H+h)*64 + jt)*2 + ot][64 lanes]

// round-to-nearest-even float -> bf16, result in TOP 16 bits
__device__ __forceinline__ unsigned bfbits(float f) {
    unsigned u = __builtin_bit_cast(unsigned, f);
    return u + 0x7fffu + ((u >> 16) & 1u);
}
// dword = (bf16(b) << 16) | bf16(a)
__device__ __forceinline__ unsigned bfpack(float a, float b) {
    return __builtin_amdgcn_perm(bfbits(b), bfbits(a), 0x07060302);
}

// ---------------------------------------------------------------------------
// Fused prep. Blocks [0,16384): adj bitmask pack (HBM stream).
// Blocks [16384,17408): MFMA projection for one (b,h,64 n-rows).
// ---------------------------------------------------------------------------
__global__ __launch_bounds__(256) void k_prep(const float* __restrict__ x,
                                              const float* __restrict__ adj,
                                              const float* __restrict__ W,
                                              const float* __restrict__ a_src,
                                              const float* __restrict__ a_dst,
                                              unsigned* __restrict__ adjb,
                                              int4* __restrict__ whf,
                                              float2* __restrict__ eap,
                                              float* __restrict__ ebe,
                                              float* __restrict__ ebe2) {
    __shared__ float wsl[FDIM * 33];          // W[h] staged, row-padded (k*33+o)
    __shared__ unsigned short wlds[64][33];   // bf16 Wh tile [local n][o], +1 pad
    int t = threadIdx.x;

    if (blockIdx.x < 16384) {
        // ---------------- adj bitmask part ----------------
        int g = blockIdx.x * 256 + t;
        int l = g & 7;
        int word = g >> 3;
        int wk = word & 63;
        int row = word >> 6;
        int i = row & (NSZ - 1);
        const float4 v = *(const float4*)&adj[(size_t)row * NSZ + wk * 32 + l * 4];
        unsigned m = 0;
        if (v.x > 0.f) m |= 1u << (l * 4 + 0);
        if (v.y > 0.f) m |= 1u << (l * 4 + 1);
        if (v.z > 0.f) m |= 1u << (l * 4 + 2);
        if (v.w > 0.f) m |= 1u << (l * 4 + 3);
        m |= (unsigned)__shfl_xor((int)m, 1);
        m |= (unsigned)__shfl_xor((int)m, 2);
        m |= (unsigned)__shfl_xor((int)m, 4);
        if (l == 0) {
            int jb = i - wk * 32;
            if (jb >= 0 && jb < 32) m |= 1u << jb;  // self-loop
            adjb[word] = m;
        }
        return;
    }

    // ---------------- projection part ----------------
    int bidx = blockIdx.x - 16384;              // [0,1024): b(2) h(3) nt(5)
    int b = bidx >> 8;
    int h = (bidx >> 5) & 7;
    int nt = bidx & 31;
    int n0 = nt * 64;
    int w = t >> 6, lane = t & 63;
    int col = lane & 15, quad = lane >> 4;

    // stage W[h] (4096 floats) coalesced into padded LDS
#pragma unroll
    for (int m = 0; m < 16; m++) {
        int idx = t + m * 256;
        wsl[(idx >> 5) * 33 + (idx & 31)] = W[(size_t)h * (FDIM * ODIM) + idx];
    }

    // A-fragments: lane(quad,col) element j = x[b][n0+w*16+col][kt*32+quad*8+j]
    const float* xp = x + ((size_t)(b * NSZ) + n0 + w * 16 + col) * FDIM + quad * 8;
    int4 afr[4];
#pragma unroll
    for (int kt = 0; kt < 4; kt++) {
        float4 xa = *(const float4*)(xp + kt * 32);
        float4 xb = *(const float4*)(xp + kt * 32 + 4);
        afr[kt] = make_int4((int)bfpack(xa.x, xa.y), (int)bfpack(xa.z, xa.w),
                            (int)bfpack(xb.x, xb.y), (int)bfpack(xb.z, xb.w));
    }
    __syncthreads();

    // build W B-frags from LDS and run 8 MFMAs
    f32x4 alo = {0.f, 0.f, 0.f, 0.f};
    f32x4 ahi = {0.f, 0.f, 0.f, 0.f};
#pragma unroll
    for (int kt = 0; kt < 4; kt++) {
        short8 a8 = __builtin_bit_cast(short8, afr[kt]);
#pragma unroll
        for (int ot = 0; ot < 2; ot++) {
            unsigned d[4];
#pragma unroll
            for (int jp = 0; jp < 4; jp++) {
                float lo = wsl[(kt * 32 + quad * 8 + 2 * jp) * 33 + ot * 16 + col];
                float hi = wsl[(kt * 32 + quad * 8 + 2 * jp + 1) * 33 + ot * 16 + col];
                d[jp] = bfpack(lo, hi);
            }
            int4 bf = make_int4((int)d[0], (int)d[1], (int)d[2], (int)d[3]);
            if (ot == 0)
                alo = __builtin_amdgcn_mfma_f32_16x16x32_bf16(a8,
                        __builtin_bit_cast(short8, bf), alo, 0, 0, 0);
            else
                ahi = __builtin_amdgcn_mfma_f32_16x16x32_bf16(a8,
                        __builtin_bit_cast(short8, bf), ahi, 0, 0, 0);
        }
    }

    // alphas: reduce Wh[row]*a over o (col lanes), then exp factors
    float as0 = a_src[h * ODIM + col], as1 = a_src[h * ODIM + 16 + col];
    float ad0 = a_dst[h * ODIM + col], ad1 = a_dst[h * ODIM + 16 + col];
#pragma unroll
    for (int r = 0; r < 4; r++) {
        float pa = alo[r] * as0 + ahi[r] * as1;
        float pb = alo[r] * ad0 + ahi[r] * ad1;
#pragma unroll
        for (int mk = 1; mk <= 8; mk <<= 1) {
            pa += __shfl_xor(pa, mk);
            pb += __shfl_xor(pb, mk);
        }
        if (col == 0) {
            size_t idx = (size_t)(b * HH + h) * NSZ + n0 + w * 16 + quad * 4 + r;
            eap[idx] = make_float2(__expf(pa - 8.f), __expf(0.2f * pa - 8.f));
            ebe[idx]  = __expf(pb - 8.f);
            ebe2[idx] = __expf(0.2f * pb - 8.f);
        }
    }

    // Wh -> LDS (bf16), then gather B-fragments: wave w does (jl=w>>1, ot=w&1)
#pragma unroll
    for (int r = 0; r < 4; r++) {
        wlds[w * 16 + quad * 4 + r][col]      = (unsigned short)(bfbits(alo[r]) >> 16);
        wlds[w * 16 + quad * 4 + r][col + 16] = (unsigned short)(bfbits(ahi[r]) >> 16);
    }
    __syncthreads();
    int jl = w >> 1, ot = w & 1;
    unsigned d[4];
#pragma unroll
    for (int jp = 0; jp < 4; jp++) {
        unsigned lo = wlds[jl * 32 + quad * 8 + 2 * jp][ot * 16 + col];
        unsigned hi = wlds[jl * 32 + quad * 8 + 2 * jp + 1][ot * 16 + col];
        d[jp] = (hi << 16) | lo;
    }
    int fragid = ((b * HH + h) * 64 + nt * 2 + jl) * 2 + ot;
    whf[(size_t)fragid * 64 + lane] = make_int4((int)d[0], (int)d[1], (int)d[2], (int)d[3]);
}

// expand mask bits (B, B+1) of w into a dword half-mask:
// bot16 = -bit(B), top16 = -bit(B+1). 3 VALU, no LDS.
template<int B>
__device__ __forceinline__ unsigned mexp2(unsigned w, unsigned selhi) {
    unsigned lo, hi, r;
    asm("v_bfe_i32 %0, %1, %2, 1" : "=v"(lo) : "v"(w), "i"(B));
    asm("v_bfe_i32 %0, %1, %2, 1" : "=v"(hi) : "v"(w), "i"(B + 1));
    asm("v_bfi_b32 %0, %1, %2, %3" : "=v"(r) : "s"(selhi), "v"(hi), "v"(lo));
    return r;
}

// masked p-fragment: 8 j's -> bf16x8 A-frag. SoA EB/EB2 pairs -> v_pk_mul +
// elementwise max + v_cvt_pk_bf16_f32; masks via bfe/bfi (no LDS traffic).
__device__ __forceinline__ int4 pfrag(float eaa, float eab,
                                      f32x4 e0, f32x4 e1, f32x4 g0, f32x4 g1,
                                      unsigned w8, unsigned selhi) {
    f32x2 ea2 = {eaa, eaa}, eb2 = {eab, eab};
    f32x2 p0 = __builtin_elementwise_max(__builtin_shufflevector(e0, e0, 0, 1) * ea2,
                                         __builtin_shufflevector(g0, g0, 0, 1) * eb2);
    f32x2 p1 = __builtin_elementwise_max(__builtin_shufflevector(e0, e0, 2, 3) * ea2,
                                         __builtin_shufflevector(g0, g0, 2, 3) * eb2);
    f32x2 p2 = __builtin_elementwise_max(__builtin_shufflevector(e1, e1, 0, 1) * ea2,
                                         __builtin_shufflevector(g1, g1, 0, 1) * eb2);
    f32x2 p3 = __builtin_elementwise_max(__builtin_shufflevector(e1, e1, 2, 3) * ea2,
                                         __builtin_shufflevector(g1, g1, 2, 3) * eb2);
    unsigned d0, d1, d2, d3;
    asm("v_cvt_pk_bf16_f32 %0, %1, %2" : "=v"(d0) : "v"(p0.x), "v"(p0.y));
    asm("v_cvt_pk_bf16_f32 %0, %1, %2" : "=v"(d1) : "v"(p1.x), "v"(p1.y));
    asm("v_cvt_pk_bf16_f32 %0, %1, %2" : "=v"(d2) : "v"(p2.x), "v"(p2.y));
    asm("v_cvt_pk_bf16_f32 %0, %1, %2" : "=v"(d3) : "v"(p3.x), "v"(p3.y));
    return make_int4((int)(d0 & mexp2<0>(w8, selhi)),
                     (int)(d1 & mexp2<2>(w8, selhi)),
                     (int)(d2 & mexp2<4>(w8, selhi)),
                     (int)(d3 & mexp2<6>(w8, selhi)));
}

// ---------------------------------------------------------------------------
// Fused masked-softmax aggregation, occupancy-optimized.
// Block = (b,h,32 i-rows): 2048 blocks = 8/CU. 4 waves = 4 jt-quarters over
// both i-tiles. VGPR capped at 64 (launch_bounds 8 waves/EU) -> 32 waves/CU.
// LDS 16KB: eb tables during loop, reused for the 2-round tree combine.
// ---------------------------------------------------------------------------
__global__ __launch_bounds__(256, 8) void k_gat(const int4* __restrict__ whf,
                                                const float2* __restrict__ eap,
                                                const float* __restrict__ ebe,
                                                const float* __restrict__ ebe2,
                                                const unsigned* __restrict__ adjb,
                                                float* __restrict__ out) {
    __shared__ __align__(16) float smem[4096];  // 16KB
    float* eble = smem;                         // EB [2048]
    float* eblf = smem + 2048;                  // EB2[2048]

    int t = threadIdx.x;
    int u = blockIdx.x;
    // XCD swizzle: XCD x gets units [x*256,(x+1)*256) = 4 consecutive (b,h)
    int unit = (u & 7) * 256 + (u >> 3);
    int b = unit >> 9;
    int h = (unit >> 6) & 7;
    int i0 = (unit & 63) * 32;
    int wave = t >> 6, lane = t & 63;
    int col = lane & 15, quad = lane >> 4, qsh = quad * 8;
    size_t bh = (size_t)(b * HH + h);
    const unsigned selhi = 0xFFFF0000u;

    // stage EB/EB2 tables: 2x 2048 floats, coalesced
    const float4* ege = (const float4*)(ebe + bh * NSZ);
    const float4* egf = (const float4*)(ebe2 + bh * NSZ);
    ((float4*)eble)[t]       = ege[t];
    ((float4*)eble)[t + 256] = ege[t + 256];
    ((float4*)eblf)[t]       = egf[t];
    ((float4*)eblf)[t + 256] = egf[t + 256];

    // per-i-tile row factors (2 tiles x 16 rows, row = i0 + tt*16 + col)
    float eaa[2], eab[2];
#pragma unroll
    for (int tt = 0; tt < 2; tt++) {
        float2 ev = eap[bh * NSZ + i0 + tt * 16 + col];
        eaa[tt] = ev.x;
        eab[tt] = ev.y;
    }
    // mask base: row (i0+tt*16+col), words [wave*16 .. wave*16+16)
    const char* mbase = (const char*)(adjb + ((size_t)(b * NSZ) + i0 + col) * 64)
                        + (size_t)wave * 64;
    const int4* bfp = whf + bh * 8192 + lane;

    f32x4 acc[2][2], accd[2];
#pragma unroll
    for (int tt = 0; tt < 2; tt++) {
        acc[tt][0] = (f32x4){0.f, 0.f, 0.f, 0.f};
        acc[tt][1] = (f32x4){0.f, 0.f, 0.f, 0.f};
        accd[tt]   = (f32x4){0.f, 0.f, 0.f, 0.f};
    }
    const int4 onesv = make_int4(0x3F803F80, 0x3F803F80, 0x3F803F80, 0x3F803F80);
    short8 bones = __builtin_bit_cast(short8, onesv);

    __syncthreads();

    for (int jt4 = 0; jt4 < 4; jt4++) {
        uint4 m0 = *(const uint4*)(mbase + 0 * 4096 + jt4 * 16);
        uint4 m1 = *(const uint4*)(mbase + 1 * 4096 + jt4 * 16);
        unsigned ma[2][4] = {{m0.x, m0.y, m0.z, m0.w},
                             {m1.x, m1.y, m1.z, m1.w}};
#pragma unroll
        for (int q = 0; q < 4; q++) {
            int jt = wave * 16 + jt4 * 4 + q;
            const f32x4* pe = (const f32x4*)&eble[jt * 32 + qsh];
            const f32x4* pf = (const f32x4*)&eblf[jt * 32 + qsh];
            f32x4 e0 = pe[0], e1 = pe[1];
            f32x4 g0 = pf[0], g1 = pf[1];
            int4 blo = bfp[jt * 128];
            int4 bhi = bfp[jt * 128 + 64];
            short8 b0 = __builtin_bit_cast(short8, blo);
            short8 b1 = __builtin_bit_cast(short8, bhi);
#pragma unroll
            for (int tt = 0; tt < 2; tt++) {
                int4 fr = pfrag(eaa[tt], eab[tt], e0, e1, g0, g1,
                                ma[tt][q] >> qsh, selhi);
                short8 af = __builtin_bit_cast(short8, fr);
                acc[tt][0] = __builtin_amdgcn_mfma_f32_16x16x32_bf16(af, b0, acc[tt][0], 0, 0, 0);
                acc[tt][1] = __builtin_amdgcn_mfma_f32_16x16x32_bf16(af, b1, acc[tt][1], 0, 0, 0);
                accd[tt]   = __builtin_amdgcn_mfma_f32_16x16x32_bf16(af, bones, accd[tt], 0, 0, 0);
            }
        }
    }

    // tree combine of 4 jt-quarter partials (reuses eb LDS; 12KB)
    f32x4 (*cb)[3][64] = (f32x4 (*)[3][64])smem;
    __syncthreads();                 // eb reads done; buffer dead
    if (wave >= 2) {
#pragma unroll
        for (int tt = 0; tt < 2; tt++) {
            int s = (wave - 2) * 2 + tt;
            cb[s][0][lane] = acc[tt][0];
            cb[s][1][lane] = acc[tt][1];
            cb[s][2][lane] = accd[tt];
        }
    }
    __syncthreads();
    if (wave < 2) {
#pragma unroll
        for (int tt = 0; tt < 2; tt++) {
            int s = wave * 2 + tt;
            acc[tt][0] += cb[s][0][lane];
            acc[tt][1] += cb[s][1][lane];
            accd[tt]   += cb[s][2][lane];
        }
    }
    __syncthreads();
    // cross-swap: wave0 sends tt=1 (slot 0), wave1 sends tt=0 (slot 1)
    if (wave == 0) {
        cb[0][0][lane] = acc[1][0];
        cb[0][1][lane] = acc[1][1];
        cb[0][2][lane] = accd[1];
    } else if (wave == 1) {
        cb[1][0][lane] = acc[0][0];
        cb[1][1][lane] = acc[0][1];
        cb[1][2][lane] = accd[0];
    }
    __syncthreads();
    if (wave >= 2) return;
    f32x4 A0, A1, AD;
    if (wave == 0) {
        A0 = acc[0][0] + cb[1][0][lane];
        A1 = acc[0][1] + cb[1][1][lane];
        AD = accd[0]   + cb[1][2][lane];
    } else {
        A0 = acc[1][0] + cb[0][0][lane];
        A1 = acc[1][1] + cb[0][1][lane];
        AD = accd[1]   + cb[0][2][lane];
    }

    // epilogue: C/D layout col=lane&15, row=quad*4+reg; AD[r] = denominator
    float* op = out + ((size_t)(b * NSZ) + i0 + wave * 16) * (HH * ODIM) + h * ODIM + col;
#pragma unroll
    for (int r = 0; r < 4; r++) {
        int row = quad * 4 + r;
        float inv = 1.0f / AD[r];
        op[(size_t)row * (HH * ODIM)]      = fmaxf(A0[r] * inv, 0.f);
        op[(size_t)row * (HH * ODIM) + 16] = fmaxf(A1[r] * inv, 0.f);
    }
}

extern "C" void kernel_launch(void* const* d_in, const int* in_sizes, int n_in,
                              void* d_out, int out_size, void* d_ws, size_t ws_size,
                              hipStream_t stream) {
    const float* x     = (const float*)d_in[0];
    const float* adj   = (const float*)d_in[1];
    const float* W     = (const float*)d_in[2];
    const float* a_src = (const float*)d_in[3];
    const float* a_dst = (const float*)d_in[4];
    float* out = (float*)d_out;

    float* ws = (float*)d_ws;
    float2* eap    = (float2*)(ws + WS_EAP);
    float* ebe     = ws + WS_EBP;
    float* ebe2    = ws + WS_EBP + 65536;
    unsigned* adjb = (unsigned*)(ws + WS_ADJB);
    int4* whf      = (int4*)(ws + WS_WHF);

    // fused prep: 16384 adj-bitmask blocks + 1024 MFMA-projection blocks
    k_prep<<<dim3(16384 + 1024), dim3(256), 0, stream>>>(x, adj, W, a_src, a_dst,
                                                         adjb, whf, eap, ebe, ebe2);
    // fused masked softmax + MFMA aggregation: 2048 blocks x 4 waves (8/CU)
    k_gat<<<dim3(BB * HH * (NSZ / 32)), dim3(256), 0, stream>>>(whf, eap, ebe, ebe2, adjb, out);
}

// Round 4
// 138.069 us; speedup vs baseline: 2.3427x; 2.3427x over previous
//
#include <hip/hip_runtime.h>
#include <math.h>

#define BB 4
#define NSZ 2048
#define FDIM 128
#define ODIM 32
#define HH 8

typedef short short8 __attribute__((ext_vector_type(8)));
typedef float f32x4 __attribute__((ext_vector_type(4)));
typedef float f32x2 __attribute__((ext_vector_type(2)));

// workspace layout (float units)
#define WS_EAP  0                 // float2[B*H*N] (EA, EA2)   = 131072 floats
#define WS_EBP  131072            // EB[B*H*N] + EB2[B*H*N]    = 131072 floats (SoA)
#define WS_ADJB 262144            // u32[B*N*64]               = 524288 words
#define WS_WHF  786432            // bf16 Wh B-frags           = 1048576 floats (4MB)
// whf: int4[((b*H+h)*64 + jt)*2 + ot][64 lanes]

// round-to-nearest-even float -> bf16, result in TOP 16 bits
__device__ __forceinline__ unsigned bfbits(float f) {
    unsigned u = __builtin_bit_cast(unsigned, f);
    return u + 0x7fffu + ((u >> 16) & 1u);
}
// dword = (bf16(b) << 16) | bf16(a)
__device__ __forceinline__ unsigned bfpack(float a, float b) {
    return __builtin_amdgcn_perm(bfbits(b), bfbits(a), 0x07060302);
}

// ---------------------------------------------------------------------------
// Fused prep. Blocks [0,16384): adj bitmask pack (HBM stream).
// Blocks [16384,17408): MFMA projection for one (b,h,64 n-rows).
// ---------------------------------------------------------------------------
__global__ __launch_bounds__(256) void k_prep(const float* __restrict__ x,
                                              const float* __restrict__ adj,
                                              const float* __restrict__ W,
                                              const float* __restrict__ a_src,
                                              const float* __restrict__ a_dst,
                                              unsigned* __restrict__ adjb,
                                              int4* __restrict__ whf,
                                              float2* __restrict__ eap,
                                              float* __restrict__ ebe,
                                              float* __restrict__ ebe2) {
    __shared__ float wsl[FDIM * 33];          // W[h] staged, row-padded (k*33+o)
    __shared__ unsigned short wlds[64][33];   // bf16 Wh tile [local n][o], +1 pad
    int t = threadIdx.x;

    if (blockIdx.x < 16384) {
        // ---------------- adj bitmask part ----------------
        int g = blockIdx.x * 256 + t;
        int l = g & 7;
        int word = g >> 3;
        int wk = word & 63;
        int row = word >> 6;
        int i = row & (NSZ - 1);
        const float4 v = *(const float4*)&adj[(size_t)row * NSZ + wk * 32 + l * 4];
        unsigned m = 0;
        if (v.x > 0.f) m |= 1u << (l * 4 + 0);
        if (v.y > 0.f) m |= 1u << (l * 4 + 1);
        if (v.z > 0.f) m |= 1u << (l * 4 + 2);
        if (v.w > 0.f) m |= 1u << (l * 4 + 3);
        m |= (unsigned)__shfl_xor((int)m, 1);
        m |= (unsigned)__shfl_xor((int)m, 2);
        m |= (unsigned)__shfl_xor((int)m, 4);
        if (l == 0) {
            int jb = i - wk * 32;
            if (jb >= 0 && jb < 32) m |= 1u << jb;  // self-loop
            adjb[word] = m;
        }
        return;
    }

    // ---------------- projection part ----------------
    int bidx = blockIdx.x - 16384;              // [0,1024): b(2) h(3) nt(5)
    int b = bidx >> 8;
    int h = (bidx >> 5) & 7;
    int nt = bidx & 31;
    int n0 = nt * 64;
    int w = t >> 6, lane = t & 63;
    int col = lane & 15, quad = lane >> 4;

    // stage W[h] (4096 floats) coalesced into padded LDS
#pragma unroll
    for (int m = 0; m < 16; m++) {
        int idx = t + m * 256;
        wsl[(idx >> 5) * 33 + (idx & 31)] = W[(size_t)h * (FDIM * ODIM) + idx];
    }

    // A-fragments: lane(quad,col) element j = x[b][n0+w*16+col][kt*32+quad*8+j]
    const float* xp = x + ((size_t)(b * NSZ) + n0 + w * 16 + col) * FDIM + quad * 8;
    int4 afr[4];
#pragma unroll
    for (int kt = 0; kt < 4; kt++) {
        float4 xa = *(const float4*)(xp + kt * 32);
        float4 xb = *(const float4*)(xp + kt * 32 + 4);
        afr[kt] = make_int4((int)bfpack(xa.x, xa.y), (int)bfpack(xa.z, xa.w),
                            (int)bfpack(xb.x, xb.y), (int)bfpack(xb.z, xb.w));
    }
    __syncthreads();

    // build W B-frags from LDS and run 8 MFMAs
    f32x4 alo = {0.f, 0.f, 0.f, 0.f};
    f32x4 ahi = {0.f, 0.f, 0.f, 0.f};
#pragma unroll
    for (int kt = 0; kt < 4; kt++) {
        short8 a8 = __builtin_bit_cast(short8, afr[kt]);
#pragma unroll
        for (int ot = 0; ot < 2; ot++) {
            unsigned d[4];
#pragma unroll
            for (int jp = 0; jp < 4; jp++) {
                float lo = wsl[(kt * 32 + quad * 8 + 2 * jp) * 33 + ot * 16 + col];
                float hi = wsl[(kt * 32 + quad * 8 + 2 * jp + 1) * 33 + ot * 16 + col];
                d[jp] = bfpack(lo, hi);
            }
            int4 bf = make_int4((int)d[0], (int)d[1], (int)d[2], (int)d[3]);
            if (ot == 0)
                alo = __builtin_amdgcn_mfma_f32_16x16x32_bf16(a8,
                        __builtin_bit_cast(short8, bf), alo, 0, 0, 0);
            else
                ahi = __builtin_amdgcn_mfma_f32_16x16x32_bf16(a8,
                        __builtin_bit_cast(short8, bf), ahi, 0, 0, 0);
        }
    }

    // alphas: reduce Wh[row]*a over o (col lanes), then exp factors
    float as0 = a_src[h * ODIM + col], as1 = a_src[h * ODIM + 16 + col];
    float ad0 = a_dst[h * ODIM + col], ad1 = a_dst[h * ODIM + 16 + col];
#pragma unroll
    for (int r = 0; r < 4; r++) {
        float pa = alo[r] * as0 + ahi[r] * as1;
        float pb = alo[r] * ad0 + ahi[r] * ad1;
#pragma unroll
        for (int mk = 1; mk <= 8; mk <<= 1) {
            pa += __shfl_xor(pa, mk);
            pb += __shfl_xor(pb, mk);
        }
        if (col == 0) {
            size_t idx = (size_t)(b * HH + h) * NSZ + n0 + w * 16 + quad * 4 + r;
            eap[idx] = make_float2(__expf(pa - 8.f), __expf(0.2f * pa - 8.f));
            ebe[idx]  = __expf(pb - 8.f);
            ebe2[idx] = __expf(0.2f * pb - 8.f);
        }
    }

    // Wh -> LDS (bf16), then gather B-fragments: wave w does (jl=w>>1, ot=w&1)
#pragma unroll
    for (int r = 0; r < 4; r++) {
        wlds[w * 16 + quad * 4 + r][col]      = (unsigned short)(bfbits(alo[r]) >> 16);
        wlds[w * 16 + quad * 4 + r][col + 16] = (unsigned short)(bfbits(ahi[r]) >> 16);
    }
    __syncthreads();
    int jl = w >> 1, ot = w & 1;
    unsigned d[4];
#pragma unroll
    for (int jp = 0; jp < 4; jp++) {
        unsigned lo = wlds[jl * 32 + quad * 8 + 2 * jp][ot * 16 + col];
        unsigned hi = wlds[jl * 32 + quad * 8 + 2 * jp + 1][ot * 16 + col];
        d[jp] = (hi << 16) | lo;
    }
    int fragid = ((b * HH + h) * 64 + nt * 2 + jl) * 2 + ot;
    whf[(size_t)fragid * 64 + lane] = make_int4((int)d[0], (int)d[1], (int)d[2], (int)d[3]);
}

// expand mask bits (B, B+1) of w into a dword half-mask:
// bot16 = -bit(B), top16 = -bit(B+1). 3 VALU, no LDS.
template<int B>
__device__ __forceinline__ unsigned mexp2(unsigned w, unsigned selhi) {
    unsigned lo, hi, r;
    asm("v_bfe_i32 %0, %1, %2, 1" : "=v"(lo) : "v"(w), "i"(B));
    asm("v_bfe_i32 %0, %1, %2, 1" : "=v"(hi) : "v"(w), "i"(B + 1));
    asm("v_bfi_b32 %0, %1, %2, %3" : "=v"(r) : "s"(selhi), "v"(hi), "v"(lo));
    return r;
}

// masked p-fragment: 8 j's -> bf16x8 A-frag. SoA EB/EB2 pairs -> v_pk_mul +
// elementwise max + v_cvt_pk_bf16_f32; masks via bfe/bfi (no LDS traffic).
__device__ __forceinline__ int4 pfrag(float eaa, float eab,
                                      f32x4 e0, f32x4 e1, f32x4 g0, f32x4 g1,
                                      unsigned w8, unsigned selhi) {
    f32x2 ea2 = {eaa, eaa}, eb2 = {eab, eab};
    f32x2 p0 = __builtin_elementwise_max(__builtin_shufflevector(e0, e0, 0, 1) * ea2,
                                         __builtin_shufflevector(g0, g0, 0, 1) * eb2);
    f32x2 p1 = __builtin_elementwise_max(__builtin_shufflevector(e0, e0, 2, 3) * ea2,
                                         __builtin_shufflevector(g0, g0, 2, 3) * eb2);
    f32x2 p2 = __builtin_elementwise_max(__builtin_shufflevector(e1, e1, 0, 1) * ea2,
                                         __builtin_shufflevector(g1, g1, 0, 1) * eb2);
    f32x2 p3 = __builtin_elementwise_max(__builtin_shufflevector(e1, e1, 2, 3) * ea2,
                                         __builtin_shufflevector(g1, g1, 2, 3) * eb2);
    unsigned d0, d1, d2, d3;
    asm("v_cvt_pk_bf16_f32 %0, %1, %2" : "=v"(d0) : "v"(p0.x), "v"(p0.y));
    asm("v_cvt_pk_bf16_f32 %0, %1, %2" : "=v"(d1) : "v"(p1.x), "v"(p1.y));
    asm("v_cvt_pk_bf16_f32 %0, %1, %2" : "=v"(d2) : "v"(p2.x), "v"(p2.y));
    asm("v_cvt_pk_bf16_f32 %0, %1, %2" : "=v"(d3) : "v"(p3.x), "v"(p3.y));
    return make_int4((int)(d0 & mexp2<0>(w8, selhi)),
                     (int)(d1 & mexp2<2>(w8, selhi)),
                     (int)(d2 & mexp2<4>(w8, selhi)),
                     (int)(d3 & mexp2<6>(w8, selhi)));
}

// ---------------------------------------------------------------------------
// Fused masked-softmax aggregation, MLP-optimized.
// Block = (b,h,32 i-rows): 2048 blocks. 4 waves = 4 jt-quarters over both
// i-tiles. Per jt4-group, ALL 10 global loads (2 mask uint4 + 8 whf int4)
// are batch-issued before the 4 q-compute steps: one miss-latency window
// per group instead of per q (R2 counters: ~1100cy stall/q = serial misses).
// NO occupancy cap (R3's forced 64-VGPR cap spilled 1GB to scratch).
// ---------------------------------------------------------------------------
__global__ __launch_bounds__(256) void k_gat(const int4* __restrict__ whf,
                                             const float2* __restrict__ eap,
                                             const float* __restrict__ ebe,
                                             const float* __restrict__ ebe2,
                                             const unsigned* __restrict__ adjb,
                                             float* __restrict__ out) {
    __shared__ __align__(16) float smem[4096];  // 16KB
    float* eble = smem;                         // EB [2048]
    float* eblf = smem + 2048;                  // EB2[2048]

    int t = threadIdx.x;
    int u = blockIdx.x;
    // XCD swizzle: XCD x gets units [x*256,(x+1)*256) = 4 consecutive (b,h)
    int unit = (u & 7) * 256 + (u >> 3);
    int b = unit >> 9;
    int h = (unit >> 6) & 7;
    int i0 = (unit & 63) * 32;
    int wave = t >> 6, lane = t & 63;
    int col = lane & 15, quad = lane >> 4, qsh = quad * 8;
    size_t bh = (size_t)(b * HH + h);
    const unsigned selhi = 0xFFFF0000u;

    // stage EB/EB2 tables: 2x 2048 floats, coalesced
    const float4* ege = (const float4*)(ebe + bh * NSZ);
    const float4* egf = (const float4*)(ebe2 + bh * NSZ);
    ((float4*)eble)[t]       = ege[t];
    ((float4*)eble)[t + 256] = ege[t + 256];
    ((float4*)eblf)[t]       = egf[t];
    ((float4*)eblf)[t + 256] = egf[t + 256];

    // per-i-tile row factors (2 tiles x 16 rows, row = i0 + tt*16 + col)
    float eaa[2], eab[2];
#pragma unroll
    for (int tt = 0; tt < 2; tt++) {
        float2 ev = eap[bh * NSZ + i0 + tt * 16 + col];
        eaa[tt] = ev.x;
        eab[tt] = ev.y;
    }
    // mask base: row (i0+tt*16+col), words [wave*16 .. wave*16+16)
    const char* mbase = (const char*)(adjb + ((size_t)(b * NSZ) + i0 + col) * 64)
                        + (size_t)wave * 64;
    const int4* bfp = whf + bh * 8192 + (size_t)(wave * 16) * 128 + lane;

    f32x4 acc[2][2], accd[2];
#pragma unroll
    for (int tt = 0; tt < 2; tt++) {
        acc[tt][0] = (f32x4){0.f, 0.f, 0.f, 0.f};
        acc[tt][1] = (f32x4){0.f, 0.f, 0.f, 0.f};
        accd[tt]   = (f32x4){0.f, 0.f, 0.f, 0.f};
    }
    const int4 onesv = make_int4(0x3F803F80, 0x3F803F80, 0x3F803F80, 0x3F803F80);
    short8 bones = __builtin_bit_cast(short8, onesv);

    __syncthreads();

    for (int jt4 = 0; jt4 < 4; jt4++) {
        // ---- batched load phase: 10 independent global loads in flight ----
        uint4 m0 = *(const uint4*)(mbase + 0 * 4096 + jt4 * 16);
        uint4 m1 = *(const uint4*)(mbase + 1 * 4096 + jt4 * 16);
        int4 blo[4], bhi[4];
#pragma unroll
        for (int q = 0; q < 4; q++) {
            blo[q] = bfp[(jt4 * 4 + q) * 128];
            bhi[q] = bfp[(jt4 * 4 + q) * 128 + 64];
        }
        unsigned ma[2][4] = {{m0.x, m0.y, m0.z, m0.w},
                             {m1.x, m1.y, m1.z, m1.w}};
        // ---- compute phase: consume with counted vmcnt ----
#pragma unroll
        for (int q = 0; q < 4; q++) {
            int jt = wave * 16 + jt4 * 4 + q;
            const f32x4* pe = (const f32x4*)&eble[jt * 32 + qsh];
            const f32x4* pf = (const f32x4*)&eblf[jt * 32 + qsh];
            f32x4 e0 = pe[0], e1 = pe[1];
            f32x4 g0 = pf[0], g1 = pf[1];
            short8 b0 = __builtin_bit_cast(short8, blo[q]);
            short8 b1 = __builtin_bit_cast(short8, bhi[q]);
#pragma unroll
            for (int tt = 0; tt < 2; tt++) {
                int4 fr = pfrag(eaa[tt], eab[tt], e0, e1, g0, g1,
                                ma[tt][q] >> qsh, selhi);
                short8 af = __builtin_bit_cast(short8, fr);
                acc[tt][0] = __builtin_amdgcn_mfma_f32_16x16x32_bf16(af, b0, acc[tt][0], 0, 0, 0);
                acc[tt][1] = __builtin_amdgcn_mfma_f32_16x16x32_bf16(af, b1, acc[tt][1], 0, 0, 0);
                accd[tt]   = __builtin_amdgcn_mfma_f32_16x16x32_bf16(af, bones, accd[tt], 0, 0, 0);
            }
        }
    }

    // tree combine of 4 jt-quarter partials (reuses eb LDS; 12KB)
    f32x4 (*cb)[3][64] = (f32x4 (*)[3][64])smem;
    __syncthreads();                 // eb reads done; buffer dead
    if (wave >= 2) {
#pragma unroll
        for (int tt = 0; tt < 2; tt++) {
            int s = (wave - 2) * 2 + tt;
            cb[s][0][lane] = acc[tt][0];
            cb[s][1][lane] = acc[tt][1];
            cb[s][2][lane] = accd[tt];
        }
    }
    __syncthreads();
    if (wave < 2) {
#pragma unroll
        for (int tt = 0; tt < 2; tt++) {
            int s = wave * 2 + tt;
            acc[tt][0] += cb[s][0][lane];
            acc[tt][1] += cb[s][1][lane];
            accd[tt]   += cb[s][2][lane];
        }
    }
    __syncthreads();
    // cross-swap: wave0 sends tt=1 (slot 0), wave1 sends tt=0 (slot 1)
    if (wave == 0) {
        cb[0][0][lane] = acc[1][0];
        cb[0][1][lane] = acc[1][1];
        cb[0][2][lane] = accd[1];
    } else if (wave == 1) {
        cb[1][0][lane] = acc[0][0];
        cb[1][1][lane] = acc[0][1];
        cb[1][2][lane] = accd[0];
    }
    __syncthreads();
    if (wave >= 2) return;
    f32x4 A0, A1, AD;
    if (wave == 0) {
        A0 = acc[0][0] + cb[1][0][lane];
        A1 = acc[0][1] + cb[1][1][lane];
        AD = accd[0]   + cb[1][2][lane];
    } else {
        A0 = acc[1][0] + cb[0][0][lane];
        A1 = acc[1][1] + cb[0][1][lane];
        AD = accd[1]   + cb[0][2][lane];
    }

    // epilogue: C/D layout col=lane&15, row=quad*4+reg; AD[r] = denominator
    float* op = out + ((size_t)(b * NSZ) + i0 + wave * 16) * (HH * ODIM) + h * ODIM + col;
#pragma unroll
    for (int r = 0; r < 4; r++) {
        int row = quad * 4 + r;
        float inv = 1.0f / AD[r];
        op[(size_t)row * (HH * ODIM)]      = fmaxf(A0[r] * inv, 0.f);
        op[(size_t)row * (HH * ODIM) + 16] = fmaxf(A1[r] * inv, 0.f);
    }
}

extern "C" void kernel_launch(void* const* d_in, const int* in_sizes, int n_in,
                              void* d_out, int out_size, void* d_ws, size_t ws_size,
                              hipStream_t stream) {
    const float* x     = (const float*)d_in[0];
    const float* adj   = (const float*)d_in[1];
    const float* W     = (const float*)d_in[2];
    const float* a_src = (const float*)d_in[3];
    const float* a_dst = (const float*)d_in[4];
    float* out = (float*)d_out;

    float* ws = (float*)d_ws;
    float2* eap    = (float2*)(ws + WS_EAP);
    float* ebe     = ws + WS_EBP;
    float* ebe2    = ws + WS_EBP + 65536;
    unsigned* adjb = (unsigned*)(ws + WS_ADJB);
    int4* whf      = (int4*)(ws + WS_WHF);

    // fused prep: 16384 adj-bitmask blocks + 1024 MFMA-projection blocks
    k_prep<<<dim3(16384 + 1024), dim3(256), 0, stream>>>(x, adj, W, a_src, a_dst,
                                                         adjb, whf, eap, ebe, ebe2);
    // fused masked softmax + MFMA aggregation: 2048 blocks x 4 waves
    k_gat<<<dim3(BB * HH * (NSZ / 32)), dim3(256), 0, stream>>>(whf, eap, ebe, ebe2, adjb, out);
}